// Round 7
// baseline (118.766 us; speedup 1.0000x reference)
//
#include <hip/hip_runtime.h>
#include <hip/hip_bf16.h>
#include <math.h>

#define T_DIM 8192
#define D_DIM 128

typedef __attribute__((ext_vector_type(8))) __bf16 bf16x8;
typedef __attribute__((ext_vector_type(16))) float f32x16;
typedef __attribute__((ext_vector_type(4))) float f32x4;

static __device__ __forceinline__ unsigned short f2bf(float f) {
    unsigned u = __builtin_bit_cast(unsigned, f);
    unsigned r = (u + 0x7FFFu + ((u >> 16) & 1u)) >> 16;
    return (unsigned short)r;
}
static __device__ __forceinline__ float bf2f(unsigned short h) {
    unsigned u = ((unsigned)h) << 16;
    return __builtin_bit_cast(float, u);
}
static __device__ __forceinline__ float exp2_fast(float x) {
    float r;
    asm("v_exp_f32 %0, %1" : "=v"(r) : "v"(x));
    return r;
}
static __device__ __forceinline__ float gelu_tanh(float x) {
    const float c = 0.7978845608028654f; // sqrt(2/pi)
    float u = c * (x + 0.044715f * x * x * x);
    float e = __expf(2.0f * u);
    float th = 1.0f - 2.0f / (e + 1.0f);
    return 0.5f * x * (1.0f + th);
}
static __device__ __forceinline__ float softplus_f(float x) {
    return (x > 20.0f) ? x : log1pf(__expf(x));
}

// ---------------------------------------------------------------------------
// prep: gelu, row-normalize -> on (row-major bf16); raw gelu -> vT' transposed
// with per-32-block column permutation sigma(k) = swap bits 2<->3 (involution).
// ---------------------------------------------------------------------------
__global__ __launch_bounds__(256) void prep_kernel(
    const float* __restrict__ x,
    unsigned short* __restrict__ on,
    unsigned short* __restrict__ vT)
{
    __shared__ unsigned short vt[32 * 128];   // [key-row][d], raw gelu bf16
    const int blk = blockIdx.x;               // 512 blocks
    const int batch = blk >> 8;
    const int kb32 = (blk & 255) << 5;
    const int t = threadIdx.x;
    const int r = t >> 3;
    const int d0 = (t & 7) << 4;

    const size_t rowbase = ((size_t)batch * T_DIM + kb32 + r) * D_DIM;
    float g[16];
    #pragma unroll
    for (int i = 0; i < 16; i += 4) {
        f32x4 xv = *reinterpret_cast<const f32x4*>(x + rowbase + d0 + i);
        g[i+0] = gelu_tanh(xv[0]); g[i+1] = gelu_tanh(xv[1]);
        g[i+2] = gelu_tanh(xv[2]); g[i+3] = gelu_tanh(xv[3]);
    }
    float ss = 0.f;
    #pragma unroll
    for (int i = 0; i < 16; ++i) ss += g[i] * g[i];
    ss += __shfl_xor(ss, 1, 64); ss += __shfl_xor(ss, 2, 64); ss += __shfl_xor(ss, 4, 64);
    const float inv = 1.0f / fmaxf(sqrtf(ss), 1e-6f);

    unsigned pk[8], vp[8];
    #pragma unroll
    for (int i = 0; i < 8; ++i) {
        pk[i] = (unsigned)f2bf(g[2*i] * inv) | ((unsigned)f2bf(g[2*i+1] * inv) << 16);
        vp[i] = (unsigned)f2bf(g[2*i])       | ((unsigned)f2bf(g[2*i+1]) << 16);
    }
    uint4 oa = {pk[0],pk[1],pk[2],pk[3]}, ob = {pk[4],pk[5],pk[6],pk[7]};
    *reinterpret_cast<uint4*>(on + rowbase + d0)     = oa;
    *reinterpret_cast<uint4*>(on + rowbase + d0 + 8) = ob;
    uint4 va = {vp[0],vp[1],vp[2],vp[3]}, vb = {vp[4],vp[5],vp[6],vp[7]};
    *reinterpret_cast<uint4*>(&vt[r * 128 + d0])     = va;
    *reinterpret_cast<uint4*>(&vt[r * 128 + d0 + 8]) = vb;

    __syncthreads();

    // write vT'[d][kb32 + pos], pos p holds key sigma(p) (swap bits 2,3)
    const int dd = t >> 1, h = (t & 1) * 16;
    unsigned short vals[16];
    #pragma unroll
    for (int j = 0; j < 16; ++j) {
        const int sj = (j & 3) | ((j & 4) << 1) | ((j & 8) >> 1);
        vals[j] = vt[(h + sj) * 128 + dd];
    }
    unsigned wp[8];
    #pragma unroll
    for (int i = 0; i < 8; ++i)
        wp[i] = (unsigned)vals[2*i] | ((unsigned)vals[2*i+1] << 16);
    uint4 wa = {wp[0],wp[1],wp[2],wp[3]}, wb = {wp[4],wp[5],wp[6],wp[7]};
    unsigned short* dst = vT + (size_t)batch * D_DIM * T_DIM + (size_t)dd * T_DIM + kb32 + h;
    *reinterpret_cast<uint4*>(dst)     = wa;
    *reinterpret_cast<uint4*>(dst + 8) = wb;
}

// ---------------------------------------------------------------------------
// attn: ONE WAVE (64 threads) owns a 64-q-row tile x 1024-key segment.
// Fully register-resident: zero LDS, zero barriers. K double-buffered in
// registers (prefetch next 32-key tile); V loaded at iter top (consumed by
// PV ~400cy later). 32x32x16 MFMA, swapped QK (A=K,B=Q), softmax in regs
// with fixed max=0 (|logit| <= 0.49 structurally), P = QK accumulator in
// natural register order (V columns sigma-permuted). Partials always written
// (nontemporal, keeps L2 clean for K/V); unified reduce does the epilogue.
// batch = blockIdx.x & 1 so each XCD (round-robin mod 8) sees ONE batch ->
// 4 MB K/V working set == its L2.
// ---------------------------------------------------------------------------
__global__ __launch_bounds__(64, 1) void attn_kernel(
    const unsigned short* __restrict__ on,
    const unsigned short* __restrict__ vT,
    const float* __restrict__ lbr,
    unsigned short* __restrict__ partO,
    float* __restrict__ partL,
    int MS)
{
    const int bx = blockIdx.x;                 // 0..255, longest tile first
    const int batch = bx & 1;
    const int tlo = bx >> 1;                   // 0..127
    const int q0 = 8128 - 64 * tlo;
    const int R = q0 + 64;
    int nseg = (R + 1023) >> 10; if (nseg > MS) nseg = MS;
    const int seg = blockIdx.y;
    if (seg >= nseg) return;
    const int len = (((R + nseg - 1) / nseg) + 31) & ~31;
    const int s0 = seg * len;
    int s1 = s0 + len; if (s1 > R) s1 = R;
    const int nit = (s1 - s0) >> 5;

    const int lane = threadIdx.x;
    const int hi = lane >> 5, cc = lane & 31;

    const float beta = fminf(softplus_f(lbr[0]), 5.0f) + 0.5f;
    const float sc2 = beta * 0.08838834764831843f * 1.4426950408889634f; // beta/sqrt(128)*log2e

    const unsigned short* onb = on + (size_t)batch * T_DIM * D_DIM;
    const unsigned short* vTb = vT + (size_t)batch * D_DIM * T_DIM;

    // Q B-fragments for both 32-col groups, pre-scaled
    bf16x8 qf0[8], qf1[8];
    #pragma unroll
    for (int dc = 0; dc < 8; ++dc) {
        bf16x8 a = *reinterpret_cast<const bf16x8*>(
            onb + (size_t)(q0 + cc) * D_DIM + dc * 16 + hi * 8);
        bf16x8 b = *reinterpret_cast<const bf16x8*>(
            onb + (size_t)(q0 + 32 + cc) * D_DIM + dc * 16 + hi * 8);
        #pragma unroll
        for (int j = 0; j < 8; ++j) {
            a[j] = (__bf16)((float)a[j] * sc2);
            b[j] = (__bf16)((float)b[j] * sc2);
        }
        qf0[dc] = a; qf1[dc] = b;
    }

    f32x16 a0[4], a1[4];
    #pragma unroll
    for (int dt = 0; dt < 4; ++dt)
        #pragma unroll
        for (int ri = 0; ri < 16; ++ri) { a0[dt][ri] = 0.f; a1[dt][ri] = 0.f; }
    float lsum0 = 0.f, lsum1 = 0.f;

    // base pointers (per-lane)
    const unsigned short* kp = onb + (size_t)(s0 + cc) * D_DIM + hi * 8;
    const unsigned short* vp0 = vTb + (size_t)(0  + cc) * T_DIM + s0 + hi * 8;
    const unsigned short* vp1 = vTb + (size_t)(32 + cc) * T_DIM + s0 + hi * 8;
    const unsigned short* vp2 = vTb + (size_t)(64 + cc) * T_DIM + s0 + hi * 8;
    const unsigned short* vp3 = vTb + (size_t)(96 + cc) * T_DIM + s0 + hi * 8;

    bf16x8 kA[8], kB[8], vC[8];   // vC[dt]=keys 0..15, vC[4+dt]=keys 16..31

#define LOADK(DST, IT) { \
    const unsigned short* p_ = kp + (size_t)(IT) * (32 * D_DIM); \
    _Pragma("unroll") \
    for (int dc_ = 0; dc_ < 8; ++dc_) \
        DST[dc_] = *reinterpret_cast<const bf16x8*>(p_ + dc_ * 16); }

#define LOADV(IT) { \
    const int o_ = (IT) * 32; \
    vC[0] = *reinterpret_cast<const bf16x8*>(vp0 + o_); \
    vC[4] = *reinterpret_cast<const bf16x8*>(vp0 + o_ + 16); \
    vC[1] = *reinterpret_cast<const bf16x8*>(vp1 + o_); \
    vC[5] = *reinterpret_cast<const bf16x8*>(vp1 + o_ + 16); \
    vC[2] = *reinterpret_cast<const bf16x8*>(vp2 + o_); \
    vC[6] = *reinterpret_cast<const bf16x8*>(vp2 + o_ + 16); \
    vC[3] = *reinterpret_cast<const bf16x8*>(vp3 + o_); \
    vC[7] = *reinterpret_cast<const bf16x8*>(vp3 + o_ + 16); }

#define COMPUTE(KS, KB_) { \
    const int kb_ = (KB_); \
    f32x16 sv0, sv1; \
    _Pragma("unroll") \
    for (int ri_ = 0; ri_ < 16; ++ri_) { sv0[ri_] = 0.f; sv1[ri_] = 0.f; } \
    _Pragma("unroll") \
    for (int dc_ = 0; dc_ < 8; ++dc_) { \
        sv0 = __builtin_amdgcn_mfma_f32_32x32x16_bf16(KS[dc_], qf0[dc_], sv0, 0, 0, 0); \
        sv1 = __builtin_amdgcn_mfma_f32_32x32x16_bf16(KS[dc_], qf1[dc_], sv1, 0, 0, 0); \
    } \
    bf16x8 p00, p01, p10, p11; \
    if (kb_ + 31 <= q0) { \
        _Pragma("unroll") \
        for (int ri_ = 0; ri_ < 16; ++ri_) { \
            float p_ = exp2_fast(sv0[ri_]); lsum0 += p_; \
            if (ri_ < 8) p00[ri_] = (__bf16)p_; else p01[ri_ - 8] = (__bf16)p_; \
        } \
    } else { \
        const int q_ = q0 + cc; \
        _Pragma("unroll") \
        for (int ri_ = 0; ri_ < 16; ++ri_) { \
            const int key_ = kb_ + (ri_ & 3) + 8 * (ri_ >> 2) + 4 * hi; \
            float p_ = exp2_fast(sv0[ri_]); \
            p_ = (key_ <= q_) ? p_ : 0.f; lsum0 += p_; \
            if (ri_ < 8) p00[ri_] = (__bf16)p_; else p01[ri_ - 8] = (__bf16)p_; \
        } \
    } \
    if (kb_ + 31 <= q0 + 32) { \
        _Pragma("unroll") \
        for (int ri_ = 0; ri_ < 16; ++ri_) { \
            float p_ = exp2_fast(sv1[ri_]); lsum1 += p_; \
            if (ri_ < 8) p10[ri_] = (__bf16)p_; else p11[ri_ - 8] = (__bf16)p_; \
        } \
    } else { \
        const int q_ = q0 + 32 + cc; \
        _Pragma("unroll") \
        for (int ri_ = 0; ri_ < 16; ++ri_) { \
            const int key_ = kb_ + (ri_ & 3) + 8 * (ri_ >> 2) + 4 * hi; \
            float p_ = exp2_fast(sv1[ri_]); \
            p_ = (key_ <= q_) ? p_ : 0.f; lsum1 += p_; \
            if (ri_ < 8) p10[ri_] = (__bf16)p_; else p11[ri_ - 8] = (__bf16)p_; \
        } \
    } \
    _Pragma("unroll") \
    for (int dt_ = 0; dt_ < 4; ++dt_) { \
        a0[dt_] = __builtin_amdgcn_mfma_f32_32x32x16_bf16(p00, vC[dt_],     a0[dt_], 0, 0, 0); \
        a0[dt_] = __builtin_amdgcn_mfma_f32_32x32x16_bf16(p01, vC[4 + dt_], a0[dt_], 0, 0, 0); \
        a1[dt_] = __builtin_amdgcn_mfma_f32_32x32x16_bf16(p10, vC[dt_],     a1[dt_], 0, 0, 0); \
        a1[dt_] = __builtin_amdgcn_mfma_f32_32x32x16_bf16(p11, vC[4 + dt_], a1[dt_], 0, 0, 0); \
    } }

    LOADK(kA, 0);
    int it = 0;
    for (; it + 2 <= nit; it += 2) {
        LOADV(it);
        LOADK(kB, it + 1);
        COMPUTE(kA, s0 + it * 32);
        LOADV(it + 1);
        if (it + 2 < nit) LOADK(kA, it + 2);
        COMPUTE(kB, s0 + (it + 1) * 32);
    }
    if (it < nit) {
        LOADV(it);
        COMPUTE(kA, s0 + it * 32);
    }
#undef LOADK
#undef LOADV
#undef COMPUTE

    // full column sums (combine the two key-halves hi)
    lsum0 += __shfl_xor(lsum0, 32, 64);
    lsum1 += __shfl_xor(lsum1, 32, 64);

    const size_t slot = (size_t)bx * MS + seg;
    unsigned short* po = partO + slot * (64 * 128);
    #pragma unroll
    for (int ri = 0; ri < 16; ++ri) {
        const int qr = (ri & 3) + 8 * (ri >> 2) + 4 * hi;
        #pragma unroll
        for (int dt = 0; dt < 4; ++dt) {
            __builtin_nontemporal_store(f2bf(a0[dt][ri]), po + qr * 128 + dt * 32 + cc);
            __builtin_nontemporal_store(f2bf(a1[dt][ri]), po + (32 + qr) * 128 + dt * 32 + cc);
        }
    }
    if (lane < 32) {
        __builtin_nontemporal_store(lsum0, partL + slot * 64 + cc);
        __builtin_nontemporal_store(lsum1, partL + slot * 64 + 32 + cc);
    }
}

// ---------------------------------------------------------------------------
// reduce: sum bf16 partials across segments + gelu epilogue (all rows)
// ---------------------------------------------------------------------------
__global__ __launch_bounds__(256) void reduce_kernel(
    const float* __restrict__ x,
    const float* __restrict__ lar,
    const unsigned short* __restrict__ partO,
    const float* __restrict__ partL,
    float* __restrict__ out,
    int MS)
{
    const int idx = blockIdx.x * 256 + threadIdx.x;  // 524288 threads
    const int row = idx >> 5;
    const int d0 = (idx & 31) << 2;
    const int batch = row >> 13, q = row & 8191;
    const int tlo = 127 - (q >> 6);
    const int R = (q & ~63) + 64;
    int nseg = (R + 1023) >> 10; if (nseg > MS) nseg = MS;
    const int roff = q & 63;
    const int bxt = tlo * 2 + batch;

    float o0 = 0.f, o1 = 0.f, o2 = 0.f, o3 = 0.f, L = 0.f;
    for (int s = 0; s < nseg; ++s) {
        const size_t slot = (size_t)bxt * MS + s;
        const unsigned short* po = partO + slot * (64 * 128) + roff * 128 + d0;
        o0 += bf2f(po[0]); o1 += bf2f(po[1]); o2 += bf2f(po[2]); o3 += bf2f(po[3]);
        L += partL[slot * 64 + roff];
    }
    const float invL = 1.0f / L;
    const float alpha = softplus_f(lar[0]);
    const size_t gi = (size_t)row * D_DIM + d0;
    const f32x4 xv = *reinterpret_cast<const f32x4*>(x + gi);
    f32x4 ov;
    const float mu[4] = {o0 * invL, o1 * invL, o2 * invL, o3 * invL};
    #pragma unroll
    for (int j = 0; j < 4; ++j) {
        const float gv = gelu_tanh(xv[j]);
        ov[j] = gv + alpha * (gv - mu[j]);
    }
    *reinterpret_cast<f32x4*>(out + gi) = ov;
}

extern "C" void kernel_launch(void* const* d_in, const int* in_sizes, int n_in,
                              void* d_out, int out_size, void* d_ws, size_t ws_size,
                              hipStream_t stream) {
    const float* x = (const float*)d_in[0];
    const float* lbr = (const float*)d_in[1];
    const float* lar = (const float*)d_in[2];
    float* out = (float*)d_out;

    unsigned short* on = (unsigned short*)d_ws;              // 4 MiB
    unsigned short* vT = on + (size_t)2 * T_DIM * D_DIM;     // 4 MiB
    const size_t fixed = (size_t)8 * 1024 * 1024;

    int MS = 1;
    {
        // per segment level: 256 tiles x (64x128 bf16 partO + 64 f32 partL)
        const long long per = 256ll * (64 * 128 * 2 + 64 * 4);
        long long avail = (long long)ws_size - (long long)fixed;
        if (avail > 0) {
            MS = (int)(avail / per);
            if (MS > 8) MS = 8;
            if (MS < 1) MS = 1;
        }
    }
    unsigned short* partO = (unsigned short*)((char*)d_ws + fixed);
    float* partL = (float*)(partO + (size_t)256 * MS * 64 * 128);

    prep_kernel<<<dim3(512), dim3(256), 0, stream>>>(x, on, vT);
    attn_kernel<<<dim3(256, MS), dim3(64), 0, stream>>>(on, vT, lbr, partO, partL, MS);
    reduce_kernel<<<dim3(2048), dim3(256), 0, stream>>>(x, lar, partO, partL, out, MS);
}

// Round 8
// 107.170 us; speedup vs baseline: 1.1082x; 1.1082x over previous
//
#include <hip/hip_runtime.h>
#include <hip/hip_bf16.h>
#include <math.h>

#define T_DIM 8192
#define D_DIM 128
#define SEG_LEN 384

typedef __attribute__((ext_vector_type(8))) __bf16 bf16x8;
typedef __attribute__((ext_vector_type(16))) float f32x16;
typedef __attribute__((ext_vector_type(4))) float f32x4;

static __device__ __forceinline__ unsigned short f2bf(float f) {
    unsigned u = __builtin_bit_cast(unsigned, f);
    unsigned r = (u + 0x7FFFu + ((u >> 16) & 1u)) >> 16;
    return (unsigned short)r;
}
static __device__ __forceinline__ float bf2f(unsigned short h) {
    unsigned u = ((unsigned)h) << 16;
    return __builtin_bit_cast(float, u);
}
static __device__ __forceinline__ float exp2_fast(float x) {
    float r;
    asm("v_exp_f32 %0, %1" : "=v"(r) : "v"(x));
    return r;
}
static __device__ __forceinline__ float gelu_tanh(float x) {
    const float c = 0.7978845608028654f; // sqrt(2/pi)
    float u = c * (x + 0.044715f * x * x * x);
    float e = __expf(2.0f * u);
    float th = 1.0f - 2.0f / (e + 1.0f);
    return 0.5f * x * (1.0f + th);
}
static __device__ __forceinline__ float softplus_f(float x) {
    return (x > 20.0f) ? x : log1pf(__expf(x));
}

// ---------------------------------------------------------------------------
// prep: gelu, row-normalize -> on (row-major bf16); raw gelu -> vT' transposed
// with per-32-block column permutation sigma(k) = swap bits 2<->3 (involution).
// ---------------------------------------------------------------------------
__global__ __launch_bounds__(256) void prep_kernel(
    const float* __restrict__ x,
    unsigned short* __restrict__ on,
    unsigned short* __restrict__ vT)
{
    __shared__ unsigned short vt[32 * 128];   // [key-row][d], raw gelu bf16
    const int blk = blockIdx.x;               // 512 blocks
    const int batch = blk >> 8;
    const int kb32 = (blk & 255) << 5;
    const int t = threadIdx.x;
    const int r = t >> 3;
    const int d0 = (t & 7) << 4;

    const size_t rowbase = ((size_t)batch * T_DIM + kb32 + r) * D_DIM;
    float g[16];
    #pragma unroll
    for (int i = 0; i < 16; i += 4) {
        f32x4 xv = *reinterpret_cast<const f32x4*>(x + rowbase + d0 + i);
        g[i+0] = gelu_tanh(xv[0]); g[i+1] = gelu_tanh(xv[1]);
        g[i+2] = gelu_tanh(xv[2]); g[i+3] = gelu_tanh(xv[3]);
    }
    float ss = 0.f;
    #pragma unroll
    for (int i = 0; i < 16; ++i) ss += g[i] * g[i];
    ss += __shfl_xor(ss, 1, 64); ss += __shfl_xor(ss, 2, 64); ss += __shfl_xor(ss, 4, 64);
    const float inv = 1.0f / fmaxf(sqrtf(ss), 1e-6f);

    unsigned pk[8], vp[8];
    #pragma unroll
    for (int i = 0; i < 8; ++i) {
        pk[i] = (unsigned)f2bf(g[2*i] * inv) | ((unsigned)f2bf(g[2*i+1] * inv) << 16);
        vp[i] = (unsigned)f2bf(g[2*i])       | ((unsigned)f2bf(g[2*i+1]) << 16);
    }
    uint4 oa = {pk[0],pk[1],pk[2],pk[3]}, ob = {pk[4],pk[5],pk[6],pk[7]};
    *reinterpret_cast<uint4*>(on + rowbase + d0)     = oa;
    *reinterpret_cast<uint4*>(on + rowbase + d0 + 8) = ob;
    uint4 va = {vp[0],vp[1],vp[2],vp[3]}, vb = {vp[4],vp[5],vp[6],vp[7]};
    *reinterpret_cast<uint4*>(&vt[r * 128 + d0])     = va;
    *reinterpret_cast<uint4*>(&vt[r * 128 + d0 + 8]) = vb;

    __syncthreads();

    // write vT'[d][kb32 + pos], pos p holds key sigma(p) (swap bits 2,3)
    const int dd = t >> 1, h = (t & 1) * 16;
    unsigned short vals[16];
    #pragma unroll
    for (int j = 0; j < 16; ++j) {
        const int sj = (j & 3) | ((j & 4) << 1) | ((j & 8) >> 1);
        vals[j] = vt[(h + sj) * 128 + dd];
    }
    unsigned wp[8];
    #pragma unroll
    for (int i = 0; i < 8; ++i)
        wp[i] = (unsigned)vals[2*i] | ((unsigned)vals[2*i+1] << 16);
    uint4 wa = {wp[0],wp[1],wp[2],wp[3]}, wb = {wp[4],wp[5],wp[6],wp[7]};
    unsigned short* dst = vT + (size_t)batch * D_DIM * T_DIM + (size_t)dd * T_DIM + kb32 + h;
    *reinterpret_cast<uint4*>(dst)     = wa;
    *reinterpret_cast<uint4*>(dst + 8) = wb;
}

// ---------------------------------------------------------------------------
// attn: ONE WAVE owns a 64-q-row tile x 384-key segment. Fully register-
// resident: zero LDS, zero barriers. K AND V double-buffered in registers
// (one full iteration of prefetch distance, ~700cy, covers L2 latency).
// 32x32x16 MFMA, swapped QK (A=K,B=Q), softmax in regs with fixed max=0
// (|logit| <= 0.49 structurally), P = QK accumulator in natural register
// order (V columns sigma-permuted). ~2600 uniform blocks keep all SIMDs fed
// at 1 wave/SIMD (~390 regs). Partials via normal stores (L3-resident).
// batch = bx&1 and XCD = linear dispatch mod 8 -> each XCD sees one batch
// (4 MB K/V working set == its L2).
// ---------------------------------------------------------------------------
__global__ __launch_bounds__(64, 1) void attn_kernel(
    const unsigned short* __restrict__ on,
    const unsigned short* __restrict__ vT,
    const float* __restrict__ lbr,
    unsigned short* __restrict__ partO,
    float* __restrict__ partL,
    int MS)
{
    const int bx = blockIdx.x;                 // 0..255, longest tile first
    const int batch = bx & 1;
    const int tlo = bx >> 1;                   // 0..127
    const int q0 = 8128 - 64 * tlo;
    const int R = q0 + 64;
    int nseg = (R + SEG_LEN - 1) / SEG_LEN; if (nseg > MS) nseg = MS;
    const int seg = blockIdx.y;
    if (seg >= nseg) return;
    const int len = (((R + nseg - 1) / nseg) + 31) & ~31;
    const int s0 = seg * len;
    int s1 = s0 + len; if (s1 > R) s1 = R;
    const int nit = (s1 - s0) >> 5;

    const int lane = threadIdx.x;
    const int hi = lane >> 5, cc = lane & 31;

    const float beta = fminf(softplus_f(lbr[0]), 5.0f) + 0.5f;
    const float sc2 = beta * 0.08838834764831843f * 1.4426950408889634f; // beta/sqrt(128)*log2e

    const unsigned short* onb = on + (size_t)batch * T_DIM * D_DIM;
    const unsigned short* vTb = vT + (size_t)batch * D_DIM * T_DIM;

    // Q B-fragments for both 32-col groups, pre-scaled
    bf16x8 qf0[8], qf1[8];
    #pragma unroll
    for (int dc = 0; dc < 8; ++dc) {
        bf16x8 a = *reinterpret_cast<const bf16x8*>(
            onb + (size_t)(q0 + cc) * D_DIM + dc * 16 + hi * 8);
        bf16x8 b = *reinterpret_cast<const bf16x8*>(
            onb + (size_t)(q0 + 32 + cc) * D_DIM + dc * 16 + hi * 8);
        #pragma unroll
        for (int j = 0; j < 8; ++j) {
            a[j] = (__bf16)((float)a[j] * sc2);
            b[j] = (__bf16)((float)b[j] * sc2);
        }
        qf0[dc] = a; qf1[dc] = b;
    }

    f32x16 a0[4], a1[4];
    #pragma unroll
    for (int dt = 0; dt < 4; ++dt)
        #pragma unroll
        for (int ri = 0; ri < 16; ++ri) { a0[dt][ri] = 0.f; a1[dt][ri] = 0.f; }
    float lsum0 = 0.f, lsum1 = 0.f;

    // base pointers (per-lane)
    const unsigned short* kp  = onb + (size_t)(s0 + cc) * D_DIM + hi * 8;
    const unsigned short* vp0 = vTb + (size_t)(0  + cc) * T_DIM + s0 + hi * 8;
    const unsigned short* vp1 = vTb + (size_t)(32 + cc) * T_DIM + s0 + hi * 8;
    const unsigned short* vp2 = vTb + (size_t)(64 + cc) * T_DIM + s0 + hi * 8;
    const unsigned short* vp3 = vTb + (size_t)(96 + cc) * T_DIM + s0 + hi * 8;

    bf16x8 kA[8], kB[8], vC[8], vD[8];  // V: [dt]=keys 0..15, [4+dt]=keys 16..31

#define LOADK(DST, IT) { \
    const unsigned short* p_ = kp + (size_t)(IT) * (32 * D_DIM); \
    _Pragma("unroll") \
    for (int dc_ = 0; dc_ < 8; ++dc_) \
        DST[dc_] = *reinterpret_cast<const bf16x8*>(p_ + dc_ * 16); }

#define LOADV(VS, IT) { \
    const int o_ = (IT) * 32; \
    VS[0] = *reinterpret_cast<const bf16x8*>(vp0 + o_); \
    VS[4] = *reinterpret_cast<const bf16x8*>(vp0 + o_ + 16); \
    VS[1] = *reinterpret_cast<const bf16x8*>(vp1 + o_); \
    VS[5] = *reinterpret_cast<const bf16x8*>(vp1 + o_ + 16); \
    VS[2] = *reinterpret_cast<const bf16x8*>(vp2 + o_); \
    VS[6] = *reinterpret_cast<const bf16x8*>(vp2 + o_ + 16); \
    VS[3] = *reinterpret_cast<const bf16x8*>(vp3 + o_); \
    VS[7] = *reinterpret_cast<const bf16x8*>(vp3 + o_ + 16); }

#define COMPUTE(KS, VS, KB_) { \
    const int kb_ = (KB_); \
    f32x16 sv0, sv1; \
    _Pragma("unroll") \
    for (int ri_ = 0; ri_ < 16; ++ri_) { sv0[ri_] = 0.f; sv1[ri_] = 0.f; } \
    _Pragma("unroll") \
    for (int dc_ = 0; dc_ < 8; ++dc_) { \
        sv0 = __builtin_amdgcn_mfma_f32_32x32x16_bf16(KS[dc_], qf0[dc_], sv0, 0, 0, 0); \
        sv1 = __builtin_amdgcn_mfma_f32_32x32x16_bf16(KS[dc_], qf1[dc_], sv1, 0, 0, 0); \
    } \
    bf16x8 p00, p01, p10, p11; \
    if (kb_ + 31 <= q0) { \
        _Pragma("unroll") \
        for (int ri_ = 0; ri_ < 16; ++ri_) { \
            float p_ = exp2_fast(sv0[ri_]); lsum0 += p_; \
            if (ri_ < 8) p00[ri_] = (__bf16)p_; else p01[ri_ - 8] = (__bf16)p_; \
        } \
    } else { \
        const int q_ = q0 + cc; \
        _Pragma("unroll") \
        for (int ri_ = 0; ri_ < 16; ++ri_) { \
            const int key_ = kb_ + (ri_ & 3) + 8 * (ri_ >> 2) + 4 * hi; \
            float p_ = exp2_fast(sv0[ri_]); \
            p_ = (key_ <= q_) ? p_ : 0.f; lsum0 += p_; \
            if (ri_ < 8) p00[ri_] = (__bf16)p_; else p01[ri_ - 8] = (__bf16)p_; \
        } \
    } \
    if (kb_ + 31 <= q0 + 32) { \
        _Pragma("unroll") \
        for (int ri_ = 0; ri_ < 16; ++ri_) { \
            float p_ = exp2_fast(sv1[ri_]); lsum1 += p_; \
            if (ri_ < 8) p10[ri_] = (__bf16)p_; else p11[ri_ - 8] = (__bf16)p_; \
        } \
    } else { \
        const int q_ = q0 + 32 + cc; \
        _Pragma("unroll") \
        for (int ri_ = 0; ri_ < 16; ++ri_) { \
            const int key_ = kb_ + (ri_ & 3) + 8 * (ri_ >> 2) + 4 * hi; \
            float p_ = exp2_fast(sv1[ri_]); \
            p_ = (key_ <= q_) ? p_ : 0.f; lsum1 += p_; \
            if (ri_ < 8) p10[ri_] = (__bf16)p_; else p11[ri_ - 8] = (__bf16)p_; \
        } \
    } \
    _Pragma("unroll") \
    for (int dt_ = 0; dt_ < 4; ++dt_) { \
        a0[dt_] = __builtin_amdgcn_mfma_f32_32x32x16_bf16(p00, VS[dt_],     a0[dt_], 0, 0, 0); \
        a0[dt_] = __builtin_amdgcn_mfma_f32_32x32x16_bf16(p01, VS[4 + dt_], a0[dt_], 0, 0, 0); \
        a1[dt_] = __builtin_amdgcn_mfma_f32_32x32x16_bf16(p10, VS[dt_],     a1[dt_], 0, 0, 0); \
        a1[dt_] = __builtin_amdgcn_mfma_f32_32x32x16_bf16(p11, VS[4 + dt_], a1[dt_], 0, 0, 0); \
    } }

    LOADK(kA, 0);
    LOADV(vC, 0);
    int it = 0;
    for (; it + 2 <= nit; it += 2) {
        LOADV(vD, it + 1);                 // prefetch next-iter V (full-iter distance)
        LOADK(kB, it + 1);                 // prefetch next-iter K
        COMPUTE(kA, vC, s0 + it * 32);
        if (it + 2 < nit) {
            LOADV(vC, it + 2);
            LOADK(kA, it + 2);
        }
        COMPUTE(kB, vD, s0 + (it + 1) * 32);
    }
    if (it < nit) {
        COMPUTE(kA, vC, s0 + it * 32);
    }
#undef LOADK
#undef LOADV
#undef COMPUTE

    // full column sums (combine the two key-halves hi)
    lsum0 += __shfl_xor(lsum0, 32, 64);
    lsum1 += __shfl_xor(lsum1, 32, 64);

    const size_t slot = (size_t)bx * MS + seg;
    unsigned short* po = partO + slot * (64 * 128);
    #pragma unroll
    for (int ri = 0; ri < 16; ++ri) {
        const int qr = (ri & 3) + 8 * (ri >> 2) + 4 * hi;
        #pragma unroll
        for (int dt = 0; dt < 4; ++dt) {
            po[qr * 128 + dt * 32 + cc]        = f2bf(a0[dt][ri]);
            po[(32 + qr) * 128 + dt * 32 + cc] = f2bf(a1[dt][ri]);
        }
    }
    if (lane < 32) {
        partL[slot * 64 + cc]      = lsum0;
        partL[slot * 64 + 32 + cc] = lsum1;
    }
}

// ---------------------------------------------------------------------------
// reduce: sum bf16 partials across segments + gelu epilogue (all rows)
// ---------------------------------------------------------------------------
__global__ __launch_bounds__(256) void reduce_kernel(
    const float* __restrict__ x,
    const float* __restrict__ lar,
    const unsigned short* __restrict__ partO,
    const float* __restrict__ partL,
    float* __restrict__ out,
    int MS)
{
    const int idx = blockIdx.x * 256 + threadIdx.x;  // 524288 threads
    const int row = idx >> 5;
    const int d0 = (idx & 31) << 2;
    const int batch = row >> 13, q = row & 8191;
    const int tlo = 127 - (q >> 6);
    const int R = (q & ~63) + 64;
    int nseg = (R + SEG_LEN - 1) / SEG_LEN; if (nseg > MS) nseg = MS;
    const int roff = q & 63;
    const int bxt = tlo * 2 + batch;

    float o0 = 0.f, o1 = 0.f, o2 = 0.f, o3 = 0.f, L = 0.f;
    for (int s = 0; s < nseg; ++s) {
        const size_t slot = (size_t)bxt * MS + s;
        const unsigned short* po = partO + slot * (64 * 128) + roff * 128 + d0;
        o0 += bf2f(po[0]); o1 += bf2f(po[1]); o2 += bf2f(po[2]); o3 += bf2f(po[3]);
        L += partL[slot * 64 + roff];
    }
    const float invL = 1.0f / L;
    const float alpha = softplus_f(lar[0]);
    const size_t gi = (size_t)row * D_DIM + d0;
    const f32x4 xv = *reinterpret_cast<const f32x4*>(x + gi);
    f32x4 ov;
    const float mu[4] = {o0 * invL, o1 * invL, o2 * invL, o3 * invL};
    #pragma unroll
    for (int j = 0; j < 4; ++j) {
        const float gv = gelu_tanh(xv[j]);
        ov[j] = gv + alpha * (gv - mu[j]);
    }
    *reinterpret_cast<f32x4*>(out + gi) = ov;
}

extern "C" void kernel_launch(void* const* d_in, const int* in_sizes, int n_in,
                              void* d_out, int out_size, void* d_ws, size_t ws_size,
                              hipStream_t stream) {
    const float* x = (const float*)d_in[0];
    const float* lbr = (const float*)d_in[1];
    const float* lar = (const float*)d_in[2];
    float* out = (float*)d_out;

    unsigned short* on = (unsigned short*)d_ws;              // 4 MiB
    unsigned short* vT = on + (size_t)2 * T_DIM * D_DIM;     // 4 MiB
    const size_t fixed = (size_t)8 * 1024 * 1024;

    int MS = 1;
    {
        // per segment level: 256 tiles x (64x128 bf16 partO + 64 f32 partL)
        const long long per = 256ll * (64 * 128 * 2 + 64 * 4);
        long long avail = (long long)ws_size - (long long)fixed;
        if (avail > 0) {
            MS = (int)(avail / per);
            if (MS > 16) MS = 16;
            if (MS < 1) MS = 1;
        }
    }
    unsigned short* partO = (unsigned short*)((char*)d_ws + fixed);
    float* partL = (float*)(partO + (size_t)256 * MS * 64 * 128);

    prep_kernel<<<dim3(512), dim3(256), 0, stream>>>(x, on, vT);
    attn_kernel<<<dim3(256, MS), dim3(64), 0, stream>>>(on, vT, lbr, partO, partL, MS);
    reduce_kernel<<<dim3(2048), dim3(256), 0, stream>>>(x, lar, partO, partL, out, MS);
}